// Round 2
// baseline (138.076 us; speedup 1.0000x reference)
//
#include <hip/hip_runtime.h>
#include <hip/hip_bf16.h>

// CrossAttentionConditionInjection — algebraic collapse.
//
// k,v are projections of `condition` (B,D) broadcast over seq, so all keys are
// identical across t => scores constant in t => softmax == 1/S exactly (power
// of 2) => attn == v exactly. Output = (condition @ Wv.T + bv) @ Wo.T + bo,
// broadcast over s. hidden_states / Wq / bq / Wk / bk are dead.
//
// R2: split-K GEMV — one block per output row (2048 blocks, 8 blocks/CU, full
// 32 waves/CU occupancy) to fix the MLP/latency bound seen in R1 (~38 µs/GEMV
// at 2 blocks/CU).

#define Bsz 4
#define Dd  2048
#define Ss  1024
#define D4  (Dd / 4)          // 512 float4 per row

// Y[b][d] = sum_e X[b][e] * W[d][e] + bias[d]
// One block (256 threads = 4 waves) per output row d; threads split the row.
__global__ __launch_bounds__(256) void gemv_rowsplit_kernel(
    const float* __restrict__ X,     // (Bsz, Dd)
    const float* __restrict__ W,     // (Dd, Dd) row-major; row d contiguous
    const float* __restrict__ bias,  // (Dd)
    float* __restrict__ Y)           // (Bsz, Dd)
{
    const int d    = blockIdx.x;
    const int tid  = threadIdx.x;
    const int lane = tid & 63;
    const int wave = tid >> 6;

    const float4* wrow = (const float4*)(W + (size_t)d * Dd);
    const float4* x4   = (const float4*)X;

    // Each thread covers f = tid and tid+256 (512 float4 per row / 256 thr).
    float acc0 = 0.f, acc1 = 0.f, acc2 = 0.f, acc3 = 0.f;
    #pragma unroll
    for (int j = 0; j < 2; ++j) {
        const int f = tid + 256 * j;
        float4 w = wrow[f];
        float4 a = x4[0 * D4 + f];
        float4 b = x4[1 * D4 + f];
        float4 c = x4[2 * D4 + f];
        float4 e = x4[3 * D4 + f];
        acc0 += w.x * a.x + w.y * a.y + w.z * a.z + w.w * a.w;
        acc1 += w.x * b.x + w.y * b.y + w.z * b.z + w.w * b.w;
        acc2 += w.x * c.x + w.y * c.y + w.z * c.z + w.w * c.w;
        ac3:
        acc3 += w.x * e.x + w.y * e.y + w.z * e.z + w.w * e.w;
    }

    // wave-level butterfly reduce (64 lanes)
    #pragma unroll
    for (int off = 32; off > 0; off >>= 1) {
        acc0 += __shfl_down(acc0, off, 64);
        acc1 += __shfl_down(acc1, off, 64);
        acc2 += __shfl_down(acc2, off, 64);
        acc3 += __shfl_down(acc3, off, 64);
    }

    // cross-wave reduce through LDS: red[wave][batch]
    __shared__ float red[4][4];
    if (lane == 0) {
        red[wave][0] = acc0;
        red[wave][1] = acc1;
        red[wave][2] = acc2;
        red[wave][3] = acc3;
    }
    __syncthreads();
    if (tid < 4) {   // tid = batch index
        float s = red[0][tid] + red[1][tid] + red[2][tid] + red[3][tid]
                + bias[d];
        Y[tid * Dd + d] = s;
    }
}

// out[b][s][d] = o[b][d]  — coalesced float4 broadcast, 32 MiB write.
__global__ __launch_bounds__(256) void bcast_kernel(
    const float* __restrict__ o,     // (Bsz, Dd)
    float* __restrict__ out)         // (Bsz, Ss, Dd)
{
    const int gid = blockIdx.x * blockDim.x + threadIdx.x;  // float4 index
    // total float4 = Bsz*Ss*D4 = 4*1024*512 = 2^21
    const int b  = gid >> 19;            // Ss*D4 = 524288 = 2^19
    const int d4 = gid & (D4 - 1);
    float4 v = ((const float4*)o)[(b << 9) | d4];
    ((float4*)out)[gid] = v;
}

extern "C" void kernel_launch(void* const* d_in, const int* in_sizes, int n_in,
                              void* d_out, int out_size, void* d_ws, size_t ws_size,
                              hipStream_t stream) {
    const float* condition = (const float*)d_in[1];
    const float* Wv = (const float*)d_in[6];
    const float* bv = (const float*)d_in[7];
    const float* Wo = (const float*)d_in[8];
    const float* bo = (const float*)d_in[9];
    float* out = (float*)d_out;

    float* tmp_v = (float*)d_ws;                 // (Bsz, Dd) = 32 KiB
    float* tmp_o = tmp_v + Bsz * Dd;             // (Bsz, Dd) = 32 KiB

    // 1) v = condition @ Wv.T + bv
    gemv_rowsplit_kernel<<<Dd, 256, 0, stream>>>(condition, Wv, bv, tmp_v);
    // 2) o = v @ Wo.T + bo
    gemv_rowsplit_kernel<<<Dd, 256, 0, stream>>>(tmp_v, Wo, bo, tmp_o);
    // 3) out[b,s,:] = o[b,:]
    const int n4 = Bsz * Ss * D4;                // 2,097,152 float4
    bcast_kernel<<<n4 / 256, 256, 0, stream>>>(tmp_o, out);
}

// Round 4
// 136.441 us; speedup vs baseline: 1.0120x; 1.0120x over previous
//
#include <hip/hip_runtime.h>
#include <hip/hip_bf16.h>

// CrossAttentionConditionInjection — algebraic collapse.
//
// k,v are projections of `condition` (B,D) broadcast over seq, so all keys
// are identical across t => scores[b,h,s,t] constant in t => softmax over a
// constant row == 1/S exactly (S=1024, power of 2, exact in fp32) =>
// attn == v exactly. Therefore:
//   out[b,s,:] = ((condition[b] @ Wv.T + bv) @ Wo.T + bo)   for all s.
// hidden_states / Wq / bq / Wk / bk are mathematically dead.
//
// R4: revert to the R1 three-kernel structure (passed, 137.66 µs).
// Evidence trail:
//  - R1 (2 blocks/CU GEMV) = 137.66 µs; R2 (8 blocks/CU GEMV) = 138.08 µs
//    → kernel-side time is invisible; window dominated by ~120 µs of harness
//    reset traffic (41 µs fillBufferAligned ×3 at 83% HBM peak in top-5).
//  - R3 cooperative fusion never launched (absmax=454 → untouched output);
//    grid.sync co-residency requirement is fragile under graph capture.
// Compulsory traffic: Wv 16 MiB + Wo 16 MiB + out 32 MiB = 64 MiB ≈ 11 µs
// at ~6 TB/s — the structural floor for the kernel-side work.

#define Bsz 4
#define Dd  2048
#define Ss  1024
#define D4  (Dd / 4)          // 512 float4 per row

// Y[b][d] = sum_e X[b][e] * W[d][e] + bias[d]
// One wave (64 lanes) per output row d. 4 waves / block => 4 rows / block.
// #pragma unroll hoists all 40 loads → enough MLP to be BW-bound.
__global__ __launch_bounds__(256) void gemv4_kernel(
    const float* __restrict__ X,     // (Bsz, Dd)
    const float* __restrict__ W,     // (Dd, Dd) row-major; row d contiguous
    const float* __restrict__ bias,  // (Dd)
    float* __restrict__ Y)           // (Bsz, Dd)
{
    const int lane = threadIdx.x & 63;
    const int wave = threadIdx.x >> 6;
    const int d    = blockIdx.x * 4 + wave;   // output row

    const float4* wrow = (const float4*)(W + (size_t)d * Dd);
    const float4* x4   = (const float4*)X;

    float acc0 = 0.f, acc1 = 0.f, acc2 = 0.f, acc3 = 0.f;
    #pragma unroll
    for (int j = 0; j < D4 / 64; ++j) {       // 8 iterations
        const int f = lane + 64 * j;
        float4 w = wrow[f];
        float4 a = x4[0 * D4 + f];
        float4 b = x4[1 * D4 + f];
        float4 c = x4[2 * D4 + f];
        float4 e = x4[3 * D4 + f];
        acc0 += w.x * a.x + w.y * a.y + w.z * a.z + w.w * a.w;
        acc1 += w.x * b.x + w.y * b.y + w.z * b.z + w.w * b.w;
        acc2 += w.x * c.x + w.y * c.y + w.z * c.z + w.w * c.w;
        acc3 += w.x * e.x + w.y * e.y + w.z * e.z + w.w * e.w;
    }
    // butterfly reduce across the 64-lane wave
    #pragma unroll
    for (int off = 32; off > 0; off >>= 1) {
        acc0 += __shfl_down(acc0, off, 64);
        acc1 += __shfl_down(acc1, off, 64);
        acc2 += __shfl_down(acc2, off, 64);
        acc3 += __shfl_down(acc3, off, 64);
    }
    if (lane == 0) {
        const float bb = bias[d];
        Y[0 * Dd + d] = acc0 + bb;
        Y[1 * Dd + d] = acc1 + bb;
        Y[2 * Dd + d] = acc2 + bb;
        Y[3 * Dd + d] = acc3 + bb;
    }
}

// out[b][s][d] = o[b][d]  — coalesced float4 broadcast, 32 MiB write.
// o is 32 KB → L2/L1-resident after first touch; writes are the cost.
__global__ __launch_bounds__(256) void bcast_kernel(
    const float* __restrict__ o,     // (Bsz, Dd)
    float* __restrict__ out)         // (Bsz, Ss, Dd)
{
    const int gid = blockIdx.x * blockDim.x + threadIdx.x;  // float4 index
    // total float4 = Bsz*Ss*D4 = 4*1024*512 = 2^21
    const int b  = gid >> 19;            // Ss*D4 = 524288 = 2^19
    const int d4 = gid & (D4 - 1);
    float4 v = ((const float4*)o)[(b << 9) | d4];
    ((float4*)out)[gid] = v;
}

extern "C" void kernel_launch(void* const* d_in, const int* in_sizes, int n_in,
                              void* d_out, int out_size, void* d_ws, size_t ws_size,
                              hipStream_t stream) {
    const float* condition = (const float*)d_in[1];
    const float* Wv = (const float*)d_in[6];
    const float* bv = (const float*)d_in[7];
    const float* Wo = (const float*)d_in[8];
    const float* bo = (const float*)d_in[9];
    float* out = (float*)d_out;

    float* tmp_v = (float*)d_ws;                 // (Bsz, Dd) = 32 KiB
    float* tmp_o = tmp_v + Bsz * Dd;             // (Bsz, Dd) = 32 KiB

    // 1) v = condition @ Wv.T + bv
    gemv4_kernel<<<Dd / 4, 256, 0, stream>>>(condition, Wv, bv, tmp_v);
    // 2) o = v @ Wo.T + bo
    gemv4_kernel<<<Dd / 4, 256, 0, stream>>>(tmp_v, Wo, bo, tmp_o);
    // 3) out[b,s,:] = o[b,:]
    const int n4 = Bsz * Ss * D4;                // 2,097,152 float4
    bcast_kernel<<<n4 / 256, 256, 0, stream>>>(tmp_o, out);
}